// Round 16
// baseline (49.504 us; speedup 1.0000x reference)
//
#include <hip/hip_runtime.h>

#define NB      32
#define NPB     16384
#define KTOP    2048
#define NF      64
#define NBINS   4096        // 12-bit bucket = key32 >> 20
#define NCH     8           // input chunks per batch (K1)
#define CROWS   2048        // rows per input chunk
#define NQ      16          // sort chunks per batch
#define CHSLOT  128         // candidate slots per sort chunk (KTOP/NQ)
#define CANDCAP 4096
#define SCAP    1024        // sort buffer capacity
#define STHR    256         // threads per sort block

// Padded LDS index for the bitonic net (u64 elements).
__device__ __forceinline__ int PAD(int i) { return i + (i >> 5); }

// Monotone map: float -> uint32 such that float order == unsigned order.
__device__ __forceinline__ unsigned mono(float f) {
  unsigned u = __float_as_uint(f);
  return (u & 0x80000000u) ? ~u : (u | 0x80000000u);
}

// K1: 256 blocks x 1024 thr (one block per 2048-row chunk): extract key
// column + private per-chunk u16 histogram (packed u32 stores).
__global__ __launch_bounds__(1024) void extract_hist_kernel(const float* __restrict__ in,
                                                            unsigned* __restrict__ keybuf,
                                                            unsigned* __restrict__ subhist32) {
  __shared__ unsigned h[NBINS];                  // 16 KiB
  const int g = blockIdx.x, tid = threadIdx.x;
  for (int i = tid; i < NBINS; i += 1024) h[i] = 0;
  __syncthreads();
  const int row0 = g * CROWS;
  unsigned k0 = mono(in[(size_t)(row0 + tid) * NF]);
  unsigned k1 = mono(in[(size_t)(row0 + tid + 1024) * NF]);
  keybuf[row0 + tid] = k0;
  keybuf[row0 + tid + 1024] = k1;
  atomicAdd(&h[k0 >> 20], 1u);
  atomicAdd(&h[k1 >> 20], 1u);
  __syncthreads();
  unsigned* out = subhist32 + (size_t)g * (NBINS / 2);
  for (int i = tid; i < NBINS / 2; i += 1024)
    out[i] = h[2 * i] | (h[2 * i + 1] << 16);    // counts <= 2048, fit u16
}

// K2: 32 blocks x 512 thr (one per batch), 8 bins/thread. Batch totals ->
// suffix scan -> D/N; chunk boundaries Ebound[q]=E(q*CHSLOT) via per-bracket
// atomicMin + suffix-min; then compact winners (bin >= D) into cand[] at
// their bucket-sorted slot (LDS counters seeded with raw ab).
__global__ __launch_bounds__(512) void scan_compact_kernel(const unsigned* __restrict__ keybuf,
                                                           const unsigned short* __restrict__ subhist,
                                                           unsigned long long* __restrict__ cand,
                                                           unsigned* __restrict__ ebound) {
  __shared__ unsigned ofs[NBINS];                // 16 KiB: raw-ab slot counters
  __shared__ unsigned wtot[8], wsfx[8];
  __shared__ unsigned Mq[NQ + 1];
  __shared__ unsigned sh_D, sh_N;
  const int b = blockIdx.x, tid = threadIdx.x;
  const int wid = tid >> 6, lane = tid & 63;

  // Totals for my 8 bins [8*tid, 8*tid+8).
  unsigned tot[8];
#pragma unroll
  for (int j = 0; j < 8; ++j) tot[j] = 0;
#pragma unroll
  for (int c = 0; c < NCH; ++c) {
    const uint4 v = *(const uint4*)(subhist + (size_t)(b * NCH + c) * NBINS + 8 * tid);
    tot[0] += v.x & 0xffffu; tot[1] += v.x >> 16;
    tot[2] += v.y & 0xffffu; tot[3] += v.y >> 16;
    tot[4] += v.z & 0xffffu; tot[5] += v.z >> 16;
    tot[6] += v.w & 0xffffu; tot[7] += v.w >> 16;
  }
  unsigned s = 0;
#pragma unroll
  for (int j = 0; j < 8; ++j) s += tot[j];

  unsigned p = s;                                // inclusive suffix over lanes
  for (int off = 1; off < 64; off <<= 1) {
    unsigned t = __shfl_down(p, off);
    if (lane + off < 64) p += t;
  }
  if (lane == 0) wtot[wid] = p;
  __syncthreads();
  if (wid == 0) {
    unsigned own = (lane < 8) ? wtot[lane] : 0;
    unsigned p2 = own;
    for (int off = 1; off < 8; off <<= 1) {
      unsigned t = __shfl_down(p2, off);
      if (lane + off < 8) p2 += t;
    }
    if (lane < 8) wsfx[lane] = p2 - own;         // totals of waves above
  }
  __syncthreads();

  unsigned run = wsfx[wid] + (p - s);            // keys strictly above my bins
  unsigned ab[8];
#pragma unroll
  for (int j = 7; j >= 0; --j) {
    ab[j] = run;                                 // above[bin 8*tid+j]
    run += tot[j];
    if (ab[j] < KTOP && run >= KTOP) {           // exactly one bin satisfies
      sh_D = (unsigned)(8 * tid + j);
      sh_N = run;
    }
  }
#pragma unroll
  for (int j = 0; j < 8; ++j) ofs[8 * tid + j] = ab[j];
  __syncthreads();                               // sh_D, sh_N visible

  // Chunk boundaries: Mq[q] = min{ab in [q*CHSLOT, (q+1)*CHSLOT)}, seed
  // Mq[NQ] = N, then suffix-min -> Ebound[q] = E(q*CHSLOT).
  if (tid < NQ) Mq[tid] = 0xffffffffu;
  if (tid == NQ) Mq[NQ] = sh_N;
  __syncthreads();
#pragma unroll
  for (int j = 0; j < 8; ++j)
    if (ab[j] < KTOP) atomicMin(&Mq[ab[j] / CHSLOT], ab[j]);
  __syncthreads();
  if (tid == 0) {
    for (int q = NQ - 1; q >= 0; --q) Mq[q] = Mq[q] < Mq[q + 1] ? Mq[q] : Mq[q + 1];
  }
  __syncthreads();
  if (tid <= NQ) ebound[b * (NQ + 1) + tid] = Mq[tid];

  // Compact winners into cand at bucket-sorted slots.
  const unsigned Dfl = sh_D << 20;
  unsigned long long* cb = cand + (size_t)b * CANDCAP;
  const uint4* kb4 = (const uint4*)(keybuf + (size_t)b * NPB);
  for (int i = tid; i < NPB / 4; i += 512) {
    uint4 kv = kb4[i];
#pragma unroll
    for (int e = 0; e < 4; ++e) {
      unsigned k = (&kv.x)[e];
      if (k >= Dfl) {
        unsigned slot = atomicAdd(&ofs[k >> 20], 1u);
        if (slot < CANDCAP) {
          unsigned li = (unsigned)(4 * i + e);   // row within batch
          cb[slot] = ((unsigned long long)k << 32) | (unsigned)~li;
        }
      }
    }
  }
}

// K3: 512 blocks (16/batch; block (b,q) owns slots [Ebound[q], Ebound[q+1])),
// 256 thr, ~8.5 KiB LDS -> several blocks/CU so sort barriers and gather
// latency overlap. Load slice of cand, bitonic-sort, gather output rows.
__global__ __launch_bounds__(STHR) void sort_gather_kernel(const float* __restrict__ in,
                                                           const unsigned long long* __restrict__ cand,
                                                           const unsigned* __restrict__ ebound,
                                                           float* __restrict__ out) {
  __shared__ unsigned long long sb[SCAP + (SCAP >> 5)];   // 8.25 KiB padded
  const int g = blockIdx.x, tid = threadIdx.x;
  const int b = g >> 4, q = g & 15;

  const unsigned E1 = ebound[b * (NQ + 1) + q];
  const unsigned E2 = ebound[b * (NQ + 1) + q + 1];
  if (E1 >= KTOP) return;                        // uniform: no output from here
  unsigned len = E2 - E1;
  if (len == 0) return;
  if (len > SCAP) len = SCAP;                    // safety (degenerate data only)

  unsigned S = 128;
  while (S < len) S <<= 1;                       // sort size, <= SCAP

  const unsigned long long* cb = cand + (size_t)b * CANDCAP;
  for (unsigned e = tid; e < len; e += STHR) sb[PAD(e)] = cb[E1 + e];
  for (unsigned e = len + tid; e < S; e += STHR) sb[PAD(e)] = 0;
  __syncthreads();

  // Bitonic sort, descending, adaptive size.
  for (unsigned size = 2; size <= S; size <<= 1) {
    for (unsigned stride = size >> 1; stride >= 1; stride >>= 1) {
      for (int t = tid; t < (int)(S / 2); t += STHR) {
        int pos = 2 * t - (t & (stride - 1));
        bool desc = ((pos & size) == 0);
        unsigned long long a = sb[PAD(pos)], bb = sb[PAD(pos + stride)];
        if (desc ? (a < bb) : (a > bb)) { sb[PAD(pos)] = bb; sb[PAD(pos + stride)] = a; }
      }
      __syncthreads();
    }
  }

  // Gather output rows [E1, gend).
  const unsigned gend = (E2 < KTOP) ? E2 : KTOP;
  int glen = (int)(gend - E1);
  if (glen > (int)len) glen = (int)len;          // safety (degenerate data only)
  const float4* inb = (const float4*)(in + (size_t)b * NPB * NF);
  float4* outb = (float4*)(out + ((size_t)b * KTOP + E1) * NF);
  for (int u = tid; u < glen * 16; u += STHR) {
    int r = u >> 4, f4 = u & 15;
    unsigned long long kv = sb[PAD(r)];
    int gi = (int)(~(unsigned)(kv & 0xffffffffu));
    outb[(size_t)r * 16 + f4] = inb[(size_t)gi * 16 + f4];
  }
}

extern "C" void kernel_launch(void* const* d_in, const int* in_sizes, int n_in,
                              void* d_out, int out_size, void* d_ws, size_t ws_size,
                              hipStream_t stream) {
  const float* in = (const float*)d_in[0];
  float* out = (float*)d_out;

  // d_ws layout: keybuf @0 (2 MiB), subhist u16 @2 MiB (2 MiB),
  // cand @4 MiB (1 MiB), ebound @5 MiB (~2.2 KB).
  unsigned* keybuf    = (unsigned*)d_ws;
  unsigned* subhist32 = (unsigned*)((char*)d_ws + (2u << 20));
  unsigned short* subhist16 = (unsigned short*)subhist32;
  unsigned long long* cand = (unsigned long long*)((char*)d_ws + (4u << 20));
  unsigned* ebound    = (unsigned*)((char*)d_ws + (5u << 20));

  extract_hist_kernel<<<NB * NCH, 1024, 0, stream>>>(in, keybuf, subhist32);
  scan_compact_kernel<<<NB, 512, 0, stream>>>(keybuf, subhist16, cand, ebound);
  sort_gather_kernel<<<NB * NQ, STHR, 0, stream>>>(in, cand, ebound, out);
}

// Round 17
// 46.611 us; speedup vs baseline: 1.0621x; 1.0621x over previous
//
#include <hip/hip_runtime.h>

#define NB      32
#define NPB     16384
#define KTOP    2048
#define NF      64
#define NBINS   4096        // 12-bit bucket = key32 >> 20
#define NCH     8           // input chunks per batch (K1)
#define CROWS   2048        // rows per input chunk
#define CHSLOT  256         // candidate slots per sort chunk (8 chunks cover KTOP)
#define SCAP    1024        // sort buffer capacity
#define STHR    512

// Padded LDS index for the bitonic net (u64 elements).
__device__ __forceinline__ int PAD(int i) { return i + (i >> 5); }

// Monotone map: float -> uint32 such that float order == unsigned order.
__device__ __forceinline__ unsigned mono(float f) {
  unsigned u = __float_as_uint(f);
  return (u & 0x80000000u) ? ~u : (u | 0x80000000u);
}

#define CESWAP(x, y, d) { if ((d) ? (r[x] < r[y]) : (r[x] > r[y])) { unsigned long long t_ = r[x]; r[x] = r[y]; r[y] = t_; } }

// K1: 256 blocks x 1024 thr (one block per 2048-row chunk): extract key
// column + private per-chunk u16 histogram (packed u32 stores).
__global__ __launch_bounds__(1024) void extract_hist_kernel(const float* __restrict__ in,
                                                            unsigned* __restrict__ keybuf,
                                                            unsigned* __restrict__ subhist32) {
  __shared__ unsigned h[NBINS];                  // 16 KiB
  const int g = blockIdx.x, tid = threadIdx.x;
  for (int i = tid; i < NBINS; i += 1024) h[i] = 0;
  __syncthreads();
  const int row0 = g * CROWS;
  unsigned k0 = mono(in[(size_t)(row0 + tid) * NF]);
  unsigned k1 = mono(in[(size_t)(row0 + tid + 1024) * NF]);
  keybuf[row0 + tid] = k0;
  keybuf[row0 + tid + 1024] = k1;
  atomicAdd(&h[k0 >> 20], 1u);
  atomicAdd(&h[k1 >> 20], 1u);
  __syncthreads();
  unsigned* out = subhist32 + (size_t)g * (NBINS / 2);
  for (int i = tid; i < NBINS / 2; i += 1024)
    out[i] = h[2 * i] | (h[2 * i + 1] << 16);    // counts <= 2048, fit u16
}

// K24: 256 blocks (8 per batch; block (b,q) owns candidate slots
// [E(256q), E(256q+256)), bin-aligned). Rebuild the batch scan from the 8
// sub-hists (L2-hot), PULL candidates from keybuf into LDS, register-blocked
// bitonic sort (8 elems/thread: strides 4,2,1 in VGPRs -> 36 barriers for
// S=1024 instead of 55), gather output rows [E1, min(E2,KTOP)).
__global__ __launch_bounds__(STHR) void select_sort_gather_kernel(const float* __restrict__ in,
                                                                  const unsigned* __restrict__ keybuf,
                                                                  const unsigned short* __restrict__ subhist,
                                                                  float* __restrict__ out) {
  __shared__ unsigned ab_lds[NBINS];             // 16 KiB: slot counters
  __shared__ unsigned long long sb[SCAP + (SCAP >> 5)];   // 8.25 KiB padded
  __shared__ unsigned wtot[8], wsfx[8];
  __shared__ unsigned shE[2];
  __shared__ unsigned sh_D, sh_N;

  const int g = blockIdx.x, tid = threadIdx.x;
  const int b = g >> 3, q = g & 7;
  const int wid = tid >> 6, lane = tid & 63;
  const unsigned x1 = (unsigned)q * CHSLOT, x2 = x1 + CHSLOT;

  if (tid < 2) shE[tid] = 0xffffffffu;

  // ---- Batch scan: totals for my 8 bins [8*tid, 8*tid+8). ----
  unsigned tot[8];
#pragma unroll
  for (int j = 0; j < 8; ++j) tot[j] = 0;
#pragma unroll
  for (int c = 0; c < NCH; ++c) {
    const uint4 v = *(const uint4*)(subhist + (size_t)(b * NCH + c) * NBINS + 8 * tid);
    tot[0] += v.x & 0xffffu; tot[1] += v.x >> 16;
    tot[2] += v.y & 0xffffu; tot[3] += v.y >> 16;
    tot[4] += v.z & 0xffffu; tot[5] += v.z >> 16;
    tot[6] += v.w & 0xffffu; tot[7] += v.w >> 16;
  }
  unsigned s = 0;
#pragma unroll
  for (int j = 0; j < 8; ++j) s += tot[j];

  unsigned p = s;                                // inclusive suffix over lanes
  for (int off = 1; off < 64; off <<= 1) {
    unsigned t = __shfl_down(p, off);
    if (lane + off < 64) p += t;
  }
  if (lane == 0) wtot[wid] = p;
  __syncthreads();
  if (wid == 0) {
    unsigned own = (lane < 8) ? wtot[lane] : 0;
    unsigned p2 = own;
    for (int off = 1; off < 8; off <<= 1) {
      unsigned t = __shfl_down(p2, off);
      if (lane + off < 8) p2 += t;
    }
    if (lane < 8) wsfx[lane] = p2 - own;         // totals of waves above
  }
  __syncthreads();

  unsigned run = wsfx[wid] + (p - s);            // keys strictly above my bins
  unsigned ab[8];
#pragma unroll
  for (int j = 7; j >= 0; --j) {
    ab[j] = run;                                 // above[bin 8*tid+j]
    run += tot[j];
    if (ab[j] < KTOP && run >= KTOP) {           // exactly one bin satisfies
      sh_D = (unsigned)(8 * tid + j);
      sh_N = run;                                // total candidate count
    }
  }

  // ---- Chunk boundaries: E1 = min ab >= x1, E2 = min ab >= x2. ----
  unsigned m1 = 0xffffffffu, m2 = 0xffffffffu;
#pragma unroll
  for (int j = 0; j < 8; ++j) {
    if (ab[j] >= x1 && ab[j] < m1) m1 = ab[j];
    if (ab[j] >= x2 && ab[j] < m2) m2 = ab[j];
  }
  for (int off = 1; off < 64; off <<= 1) {
    unsigned t1 = __shfl_xor(m1, off), t2 = __shfl_xor(m2, off);
    m1 = m1 < t1 ? m1 : t1;
    m2 = m2 < t2 ? m2 : t2;
  }
  if (lane == 0) { atomicMin(&shE[0], m1); atomicMin(&shE[1], m2); }
  __syncthreads();

  const unsigned D = sh_D, N = sh_N;
  const unsigned E1 = shE[0];
  unsigned E2 = (x2 >= N) ? N : shE[1];
  if (E2 > N) E2 = N;
  if (E1 >= KTOP || E1 >= N) return;             // uniform exit: no output here
  unsigned len = E2 - E1;
  if (len == 0) return;
  if (len > SCAP) len = SCAP;                    // safety (degenerate data only)

  // ---- Seed slot counters (ab - E1; foreign bins wrap/overflow -> reject). ----
#pragma unroll
  for (int j = 0; j < 8; ++j) ab_lds[8 * tid + j] = ab[j] - E1;
  unsigned S = 256;
  while (S < len) S <<= 1;                       // sort size, <= SCAP
  for (unsigned e = len + tid; e < S; e += STHR) sb[PAD(e)] = 0;
  __syncthreads();

  // ---- Pull candidates: scan the batch's 16K keys (L2-hot). ----
  const unsigned Dfl = D << 20;
  const uint4* kb4 = (const uint4*)(keybuf + (size_t)b * NPB);
  for (int i = tid; i < NPB / 4; i += STHR) {
    uint4 kv = kb4[i];
#pragma unroll
    for (int e = 0; e < 4; ++e) {
      unsigned k = (&kv.x)[e];
      if (k >= Dfl) {                            // bin >= D (candidate anywhere)
        unsigned bin = k >> 20;
        if (ab_lds[bin] < len) {                 // racy pre-check (monotonic-safe)
          unsigned slot = atomicAdd(&ab_lds[bin], 1u);
          if (slot < len) {
            unsigned li = (unsigned)(4 * i + e); // row within batch
            sb[PAD(slot)] = ((unsigned long long)k << 32) | (unsigned)~li;
          }
        }
      }
    }
  }
  __syncthreads();

  // ---- Register-blocked bitonic sort (8 elems/thread), descending. ----
  const int T = (int)(S >> 3);                   // threads owning 8 elements
  if (tid < T) {                                 // presort run tid (desc iff even)
    unsigned long long r[8];
#pragma unroll
    for (int i = 0; i < 8; ++i) r[i] = sb[PAD(8 * tid + i)];
    const bool d = ((tid & 1) == 0);
    // size 2: desc iff (i & 2)==0
    CESWAP(0,1,true); CESWAP(2,3,false); CESWAP(4,5,true); CESWAP(6,7,false);
    // size 4: desc iff (i & 4)==0
    CESWAP(0,2,true); CESWAP(1,3,true); CESWAP(4,6,false); CESWAP(5,7,false);
    CESWAP(0,1,true); CESWAP(2,3,true); CESWAP(4,5,false); CESWAP(6,7,false);
    // size 8: direction d
    CESWAP(0,4,d); CESWAP(1,5,d); CESWAP(2,6,d); CESWAP(3,7,d);
    CESWAP(0,2,d); CESWAP(1,3,d); CESWAP(4,6,d); CESWAP(5,7,d);
    CESWAP(0,1,d); CESWAP(2,3,d); CESWAP(4,5,d); CESWAP(6,7,d);
#pragma unroll
    for (int i = 0; i < 8; ++i) sb[PAD(8 * tid + i)] = r[i];
  }
  __syncthreads();

  for (unsigned size = 16; size <= S; size <<= 1) {
    for (unsigned stride = size >> 1; stride >= 8; stride >>= 1) {
      for (int c = tid; c < (int)(S / 2); c += STHR) {
        int pos = 2 * c - (c & ((int)stride - 1));
        bool desc = ((pos & size) == 0);
        unsigned long long a = sb[PAD(pos)], bb = sb[PAD(pos + (int)stride)];
        if (desc ? (a < bb) : (a > bb)) { sb[PAD(pos)] = bb; sb[PAD(pos + (int)stride)] = a; }
      }
      __syncthreads();
    }
    if (tid < T) {                               // strides 4,2,1 in registers
      unsigned long long r[8];
#pragma unroll
      for (int i = 0; i < 8; ++i) r[i] = sb[PAD(8 * tid + i)];
      const bool d = (((8u * (unsigned)tid) & size) == 0);
      CESWAP(0,4,d); CESWAP(1,5,d); CESWAP(2,6,d); CESWAP(3,7,d);
      CESWAP(0,2,d); CESWAP(1,3,d); CESWAP(4,6,d); CESWAP(5,7,d);
      CESWAP(0,1,d); CESWAP(2,3,d); CESWAP(4,5,d); CESWAP(6,7,d);
#pragma unroll
      for (int i = 0; i < 8; ++i) sb[PAD(8 * tid + i)] = r[i];
    }
    __syncthreads();
  }

  // ---- Gather output rows [E1, gend). ----
  const unsigned gend = (E2 < KTOP) ? E2 : KTOP;
  const int glen = (int)(gend - E1);
  const float4* inb = (const float4*)(in + (size_t)b * NPB * NF);
  float4* outb = (float4*)(out + ((size_t)b * KTOP + E1) * NF);
  for (int u = tid; u < glen * 16; u += STHR) {
    int r = u >> 4, f4 = u & 15;
    unsigned long long kv = sb[PAD(r)];
    int gi = (int)(~(unsigned)(kv & 0xffffffffu));
    outb[(size_t)r * 16 + f4] = inb[(size_t)gi * 16 + f4];
  }
}

extern "C" void kernel_launch(void* const* d_in, const int* in_sizes, int n_in,
                              void* d_out, int out_size, void* d_ws, size_t ws_size,
                              hipStream_t stream) {
  const float* in = (const float*)d_in[0];
  float* out = (float*)d_out;

  // d_ws layout: keybuf @0 (2 MiB), subhist u16 @2 MiB (2 MiB).
  unsigned* keybuf    = (unsigned*)d_ws;
  unsigned* subhist32 = (unsigned*)((char*)d_ws + (2u << 20));
  unsigned short* subhist16 = (unsigned short*)subhist32;

  extract_hist_kernel<<<NB * NCH, 1024, 0, stream>>>(in, keybuf, subhist32);
  select_sort_gather_kernel<<<NB * NCH, STHR, 0, stream>>>(in, keybuf, subhist16, out);
}